// Round 15
// baseline (92.557 us; speedup 1.0000x reference)
//
#include <hip/hip_runtime.h>
#include <stdint.h>

// Problem constants
#define NN 16384                  // sampled points per batch (h*w)
#define HW 65536                  // H*W
#define OUT_HALF (2 * NN * 128)   // one tuple element, flat floats
#define NP 8                      // points per wave (plain sequential loop)
// MLP: 67 -> 64 -> 64 -> 128 (BN folded), maxpool over K=32 neighbors.
//
// Round-15 = round-14 body (90.6 us, absmax 1.22e-4) with TWO changes:
//  (1) each wave processes NP=8 points in a PLAIN loop (no pipelining, no
//      cross-iteration state -- r6/r7/r12 failed on staging registers, this
//      adds only a loop counter). Grid 512 blocks = exactly 2/CU, ALL
//      co-resident -> single block generation, weight fill paid once:
//      fill traffic 268 MB -> 36 MB, no generation serialization.
//  (2) bias + X0 weights move into LDS using r12's PROVEN uncompacted
//      layout (full 70656 B fill) -- avoids the compiler hoisting ~68
//      loop-invariant bias VGPRs out of the point loop.
// 2-pass MFMA: weights plain bf16-hi; activations hi/lo split (w*ah + w*al).
//
// Dataflow (m74/m101-verified maps):
//   L0/L1 operand-swapped (A=W, B=act) -> C/D col = lane&31 = neighbor.
//   Transitions in-register: relu -> cvt_pk hi/lo split -> permlane32_swap.
//   L2 normal (A=act, B=W); maxpool = 16 fmax + xor(32); kh halves store the
//   two tuple copies.
//
// Fragment maps (gfx950 32x32x16 bf16):
//   A: row = lane&31, k = 8*(lane>>5)+e ;  B: col = lane&31, same k
//   C/D: col = lane&31, row = (rg&3) + 8*(rg>>2) + 4*(lane>>5)

typedef __attribute__((ext_vector_type(8)))  short bf16x8;
typedef __attribute__((ext_vector_type(16))) float f32x16;

// ws layout, uint16 units (IDENTICAL to rounds 11/12/14).
//  L0 hi (kt 0..3) @ 0      [4 kt][2 tile][64 lane][8 e] = 4096
//  L0 lo           @ 4096   (written by prep, unread by main -- kept for
//  L1 hi           @ 8192    layout identity with the proven kernels)
//  L1 lo           @ 12288
//  L2 hi           @ 16384
//  L2 lo           @ 24576
//  L0 xyz-step hi  @ 32768  [2 tile][64][8] = 1024
//  L0 xyz-step lo  @ 33792
//  bias            @ 34816  f32[256]: bias0[64], bias1[64], bias2[128]
#define WS_L0H 0
#define WS_L0L 4096
#define WS_L1H 8192
#define WS_L1L 12288
#define WS_L2H 16384
#define WS_L2L 24576
#define WS_X0H 32768
#define WS_X0L 33792
#define WS_BIAS 34816
#define WS_TOTAL_U16 35328        // 70656 B, ALL LDS-resident (r12-proven)
#define WS_TOTAL_U4  4416

__device__ inline uint16_t f32_to_bf16_rne(float x) {
    uint32_t u = __float_as_uint(x);
    uint32_t r = (u + 0x7FFFu + ((u >> 16) & 1u)) >> 16;
    return (uint16_t)r;
}
__device__ inline float bf16_hi_f32(uint16_t h) {
    return __uint_as_float(((uint32_t)h) << 16);
}
__device__ inline void split2(float v, uint16_t* hi, uint16_t* lo) {
    uint16_t h = f32_to_bf16_rne(v);
    *hi = h;
    *lo = f32_to_bf16_rne(v - bf16_hi_f32(h));
}

// ---------------- weight prep (runs once per launch, tiny) ----------------
// IDENTICAL to rounds 11/14.
__global__ void prep_weights(
    const float* __restrict__ W0, const float* __restrict__ b0,
    const float* __restrict__ g0, const float* __restrict__ be0,
    const float* __restrict__ W1, const float* __restrict__ b1,
    const float* __restrict__ g1, const float* __restrict__ be1,
    const float* __restrict__ W2, const float* __restrict__ b2,
    const float* __restrict__ g2, const float* __restrict__ be2,
    uint16_t* __restrict__ ws)
{
    const int tid = blockIdx.x * blockDim.x + threadIdx.x;
    const int nth = gridDim.x * blockDim.x;

    for (int i = tid; i < 4096; i += nth) {
        int e = i & 7, lane = (i >> 3) & 63, nt = (i >> 9) & 1, kt = i >> 10;
        int k = kt * 16 + 8 * (lane >> 5) + e;
        int n = nt * 32 + (lane & 31);
        float v = W0[(3 + k) * 64 + n] * g0[n];
        uint16_t hi, lo; split2(v, &hi, &lo);
        ws[WS_L0H + i] = hi; ws[WS_L0L + i] = lo;
    }
    for (int i = tid; i < 1024; i += nth) {
        int e = i & 7, lane = (i >> 3) & 63, nt = i >> 9;
        int k = 64 + 8 * (lane >> 5) + e;
        int n = nt * 32 + (lane & 31);
        float v = (k < 67) ? W0[(k - 64) * 64 + n] * g0[n] : 0.f;
        uint16_t hi, lo; split2(v, &hi, &lo);
        ws[WS_X0H + i] = hi; ws[WS_X0L + i] = lo;
    }
    for (int i = tid; i < 4096; i += nth) {
        int e = i & 7, lane = (i >> 3) & 63, nt = (i >> 9) & 1, kt = i >> 10;
        int k = kt * 16 + 8 * (lane >> 5) + e;
        int n = nt * 32 + (lane & 31);
        float v = W1[k * 64 + n] * g1[n];
        uint16_t hi, lo; split2(v, &hi, &lo);
        ws[WS_L1H + i] = hi; ws[WS_L1L + i] = lo;
    }
    for (int i = tid; i < 8192; i += nth) {
        int e = i & 7, lane = (i >> 3) & 63, nt = (i >> 9) & 3, kt = i >> 11;
        int k = kt * 16 + 8 * (lane >> 5) + e;
        int n = nt * 32 + (lane & 31);
        float v = W2[k * 128 + n] * g2[n];
        uint16_t hi, lo; split2(v, &hi, &lo);
        ws[WS_L2H + i] = hi; ws[WS_L2L + i] = lo;
    }
    float* bias = (float*)(ws + WS_BIAS);
    for (int i = tid; i < 64; i += nth)  bias[i]       = b0[i] * g0[i] + be0[i];
    for (int i = tid; i < 64; i += nth)  bias[64 + i]  = b1[i] * g1[i] + be1[i];
    for (int i = tid; i < 128; i += nth) bias[128 + i] = b2[i] * g2[i] + be2[i];
}

// ---------------- main kernel helpers ----------------
__device__ inline uint32_t cvt_pk_bf16(float a, float b) {
    uint32_t r;
    asm("v_cvt_pk_bf16_f32 %0, %1, %2" : "=v"(r) : "v"(a), "v"(b));
    return r;
}

union frag_u { uint32_t w[4]; bf16x8 v; };

// split 8 f32 -> hi/lo bf16x8 via packed converts (lo = a - f32(hi), exact)
__device__ inline void split8(const float* f, bf16x8* hi, bf16x8* lo) {
    frag_u H, L;
    #pragma unroll
    for (int p2 = 0; p2 < 4; ++p2) {
        float a = f[2 * p2], b = f[2 * p2 + 1];
        uint32_t h = cvt_pk_bf16(a, b);
        float ha = __uint_as_float(h << 16);
        float hb = __uint_as_float(h & 0xffff0000u);
        uint32_t l = cvt_pk_bf16(a - ha, b - hb);
        H.w[p2] = h; L.w[p2] = l;
    }
    *hi = H.v; *lo = L.v;
}

// L0/L1 (swapped): D += W * (act_hi + act_lo); weights plain bf16-hi.
__device__ inline f32x16 mfma2_WA(bf16x8 w, bf16x8 bh, bf16x8 bl, f32x16 c) {
    c = __builtin_amdgcn_mfma_f32_32x32x16_bf16(w, bh, c, 0, 0, 0);
    c = __builtin_amdgcn_mfma_f32_32x32x16_bf16(w, bl, c, 0, 0, 0);
    return c;
}
// L2 (normal): D += (act_hi + act_lo) * W
__device__ inline f32x16 mfma2_AW(bf16x8 ah, bf16x8 al, bf16x8 w, f32x16 c) {
    c = __builtin_amdgcn_mfma_f32_32x32x16_bf16(ah, w, c, 0, 0, 0);
    c = __builtin_amdgcn_mfma_f32_32x32x16_bf16(al, w, c, 0, 0, 0);
    return c;
}

// relu + hi/lo split + permlane32_swap assembly of next layer's K-fragments.
__device__ inline void transition(const f32x16* acc, bf16x8* fh, bf16x8* fl) {
    #pragma unroll
    for (int mt = 0; mt < 2; ++mt) {
        uint32_t H[8], L[8];
        #pragma unroll
        for (int w = 0; w < 8; ++w) {
            float a = fmaxf(acc[mt][2 * w],     0.f);
            float b = fmaxf(acc[mt][2 * w + 1], 0.f);
            uint32_t h = cvt_pk_bf16(a, b);
            float ha = __uint_as_float(h << 16);
            float hb = __uint_as_float(h & 0xffff0000u);
            H[w] = h;
            L[w] = cvt_pk_bf16(a - ha, b - hb);
        }
        #pragma unroll
        for (int ktL = 0; ktL < 2; ++ktL) {
            uint32_t a0 = H[4 * ktL + 0], b0 = H[4 * ktL + 2];
            uint32_t a1 = H[4 * ktL + 1], b1 = H[4 * ktL + 3];
            asm("v_permlane32_swap_b32 %0, %1" : "+v"(a0), "+v"(b0));
            asm("v_permlane32_swap_b32 %0, %1" : "+v"(a1), "+v"(b1));
            uint32_t c0 = L[4 * ktL + 0], d0 = L[4 * ktL + 2];
            uint32_t c1 = L[4 * ktL + 1], d1 = L[4 * ktL + 3];
            asm("v_permlane32_swap_b32 %0, %1" : "+v"(c0), "+v"(d0));
            asm("v_permlane32_swap_b32 %0, %1" : "+v"(c1), "+v"(d1));
            frag_u F; F.w[0] = a0; F.w[1] = a1; F.w[2] = b0; F.w[3] = b1;
            frag_u G; G.w[0] = c0; G.w[1] = c1; G.w[2] = d0; G.w[3] = d1;
            fh[mt * 2 + ktL] = F.v;
            fl[mt * 2 + ktL] = G.v;
        }
    }
}

__global__ __launch_bounds__(512)
void pointnet_mfma(
    const float* __restrict__ xyz_proj,      // [B, H*W, 3]
    const float* __restrict__ points_proj,   // [B, H*W, 64]
    const float* __restrict__ xyz_sampled,   // [B, N, 3]
    const int*   __restrict__ nidx,          // [B, N, 32]
    const float* __restrict__ vmask,         // [B, N, 32, 1]
    const uint16_t* __restrict__ wf,
    float* __restrict__ out)
{
    __shared__ __align__(16) uint16_t slds[WS_TOTAL_U16];  // 70656 B (r12-proven)

    // ---- cooperative fill then ONE barrier; waves independent after ----
    {
        const uint4* src = (const uint4*)wf;
        uint4* dst = (uint4*)slds;
        for (int i = threadIdx.x; i < WS_TOTAL_U4; i += 512)
            dst[i] = src[i];
    }
    __syncthreads();

    // XCD-aware bijective swizzle (grid 512, 8 XCDs, 64 blocks per XCD)
    const int bid = blockIdx.x;
    const int swz = (bid & 7) * 64 + (bid >> 3);

    const int t     = threadIdx.x & 63;
    const int widx  = threadIdx.x >> 6;        // 0..7
    const int pbase = (swz * 8 + widx) * NP;   // NP consecutive points

    const int r  = t & 31;   // this lane's neighbor (col) all the way through
    const int kh = t >> 5;   // k-half selector

    const bf16x8* L0h = (const bf16x8*)(slds + WS_L0H);
    const bf16x8* L1h = (const bf16x8*)(slds + WS_L1H);
    const bf16x8* L2h = (const bf16x8*)(slds + WS_L2H);
    const bf16x8* X0h = (const bf16x8*)(slds + WS_X0H);
    const float*  bias = (const float*)(slds + WS_BIAS);

    #pragma unroll 1
    for (int it = 0; it < NP; ++it) {
        const int p  = pbase + it;
        const int rb = (p >> 14) << 16;        // b * HW

        // ---- per-neighbor scalars (each lane: its own neighbor) ----
        const int   idx = nidx[(size_t)p * 32 + r];
        const float m   = vmask[(size_t)p * 32 + r];
        float xd0, xd1, xd2;
        {
            const float* xs = xyz_proj + (size_t)(rb + idx) * 3;
            const float* ns = xyz_sampled + (size_t)p * 3;
            xd0 = xs[0] * m - ns[0];
            xd1 = xs[1] * m - ns[1];
            xd2 = xs[2] * m - ns[2];
        }
        const float* rowp = points_proj + (size_t)(rb + idx) * 64 + 8 * kh;

        // ---- layer 0: K = 64 (channels) + 3 (xyz) -> 64, swapped (W=A) ----
        f32x16 acc0[2];
        #pragma unroll
        for (int mt = 0; mt < 2; ++mt)
            #pragma unroll
            for (int q = 0; q < 4; ++q) {
                float4 bq = *(const float4*)(bias + mt * 32 + 4 * kh + 8 * q);
                acc0[mt][4 * q + 0] = bq.x; acc0[mt][4 * q + 1] = bq.y;
                acc0[mt][4 * q + 2] = bq.z; acc0[mt][4 * q + 3] = bq.w;
            }
        #pragma unroll
        for (int kt = 0; kt < 4; ++kt) {
            bf16x8 w0 = L0h[(kt * 2 + 0) * 64 + t];
            bf16x8 w1 = L0h[(kt * 2 + 1) * 64 + t];
            float f[8];
            *(float4*)&f[0] = ((const float4*)(rowp + kt * 16))[0];
            *(float4*)&f[4] = ((const float4*)(rowp + kt * 16))[1];
            #pragma unroll
            for (int e = 0; e < 8; ++e) f[e] *= m;
            bf16x8 bh, bl; split8(f, &bh, &bl);
            acc0[0] = mfma2_WA(w0, bh, bl, acc0[0]);
            acc0[1] = mfma2_WA(w1, bh, bl, acc0[1]);
        }
        {   // xyz k-step (k 64..66 live in kh==0 lanes, e<3)
            bf16x8 w0 = X0h[0 * 64 + t];
            bf16x8 w1 = X0h[1 * 64 + t];
            const bool lo32 = (kh == 0);
            float f[8] = { lo32 ? xd0 : 0.f, lo32 ? xd1 : 0.f, lo32 ? xd2 : 0.f,
                           0.f, 0.f, 0.f, 0.f, 0.f };
            bf16x8 bh, bl; split8(f, &bh, &bl);
            acc0[0] = mfma2_WA(w0, bh, bl, acc0[0]);
            acc0[1] = mfma2_WA(w1, bh, bl, acc0[1]);
        }

        // ---- transition 1: relu+split+swap -> L1 B-fragments ----
        bf16x8 fh[4], fl[4];
        transition(acc0, fh, fl);

        // ---- layer 1: 64 -> 64, swapped (W=A) ----
        f32x16 acc1[2];
        #pragma unroll
        for (int mt = 0; mt < 2; ++mt)
            #pragma unroll
            for (int q = 0; q < 4; ++q) {
                float4 bq = *(const float4*)(bias + 64 + mt * 32 + 4 * kh + 8 * q);
                acc1[mt][4 * q + 0] = bq.x; acc1[mt][4 * q + 1] = bq.y;
                acc1[mt][4 * q + 2] = bq.z; acc1[mt][4 * q + 3] = bq.w;
            }
        #pragma unroll
        for (int kt = 0; kt < 4; ++kt) {
            bf16x8 w0 = L1h[(kt * 2 + 0) * 64 + t];
            bf16x8 w1 = L1h[(kt * 2 + 1) * 64 + t];
            acc1[0] = mfma2_WA(w0, fh[kt], fl[kt], acc1[0]);
            acc1[1] = mfma2_WA(w1, fh[kt], fl[kt], acc1[1]);
        }

        // ---- transition 2 -> L2 A-fragments (same per-lane layout) ----
        bf16x8 gh[4], gl[4];
        transition(acc1, gh, gl);

        // ---- layer 2: 64 -> 128, normal (act=A); fused maxpool + store ----
        #pragma unroll
        for (int half = 0; half < 2; ++half) {
            f32x16 acc2[2];
            const float bb0 = bias[128 + (half * 2 + 0) * 32 + r];
            const float bb1 = bias[128 + (half * 2 + 1) * 32 + r];
            #pragma unroll
            for (int i = 0; i < 16; ++i) { acc2[0][i] = bb0; acc2[1][i] = bb1; }
            #pragma unroll
            for (int kt = 0; kt < 4; ++kt) {
                bf16x8 w0 = L2h[(kt * 4 + half * 2 + 0) * 64 + t];
                bf16x8 w1 = L2h[(kt * 4 + half * 2 + 1) * 64 + t];
                acc2[0] = mfma2_AW(gh[kt], gl[kt], w0, acc2[0]);
                acc2[1] = mfma2_AW(gh[kt], gl[kt], w1, acc2[1]);
            }
            #pragma unroll
            for (int j = 0; j < 2; ++j) {
                float v = acc2[j][0];
                #pragma unroll
                for (int g = 1; g < 16; ++g) v = fmaxf(v, acc2[j][g]);
                v = fmaxf(v, __shfl_xor(v, 32));   // merge kh halves
                v = fmaxf(v, 0.f);                 // relu commutes with max
                // kh=0 lanes store tuple copy 0, kh=1 lanes store copy 1
                size_t o = (size_t)p * 128 + (half * 2 + j) * 32 + r
                         + (size_t)kh * OUT_HALF;
                out[o] = v;
            }
        }
    }
}

extern "C" void kernel_launch(void* const* d_in, const int* in_sizes, int n_in,
                              void* d_out, int out_size, void* d_ws, size_t ws_size,
                              hipStream_t stream) {
    const float* xyz_proj    = (const float*)d_in[0];
    const float* points_proj = (const float*)d_in[1];
    const float* xyz_sampled = (const float*)d_in[2];
    const int*   neighbor_idx= (const int*)  d_in[3];
    const float* valid_mask  = (const float*)d_in[4];
    const float* W0 = (const float*)d_in[5];
    const float* b0 = (const float*)d_in[6];
    const float* g0 = (const float*)d_in[7];
    const float* be0= (const float*)d_in[8];
    const float* W1 = (const float*)d_in[9];
    const float* b1 = (const float*)d_in[10];
    const float* g1 = (const float*)d_in[11];
    const float* be1= (const float*)d_in[12];
    const float* W2 = (const float*)d_in[13];
    const float* b2 = (const float*)d_in[14];
    const float* g2 = (const float*)d_in[15];
    const float* be2= (const float*)d_in[16];

    uint16_t* ws = (uint16_t*)d_ws;

    prep_weights<<<64, 256, 0, stream>>>(W0, b0, g0, be0,
                                         W1, b1, g1, be1,
                                         W2, b2, g2, be2, ws);

    // 32768 points: 8 per wave, 8 waves per block -> 512 blocks (2/CU, all
    // co-resident -> single generation, weight fill paid once per block)
    pointnet_mfma<<<512, 512, 0, stream>>>(
        xyz_proj, points_proj, xyz_sampled, neighbor_idx, valid_mask,
        ws, (float*)d_out);
}

// Round 16
// 90.691 us; speedup vs baseline: 1.0206x; 1.0206x over previous
//
#include <hip/hip_runtime.h>
#include <stdint.h>

// Problem constants
#define NN 16384                  // sampled points per batch (h*w)
#define HW 65536                  // H*W
#define OUT_HALF (2 * NN * 128)   // one tuple element, flat floats
// MLP: 67 -> 64 -> 64 -> 128 (BN folded), maxpool over K=32 neighbors.
//
// Round-16 = EXACT round-14 kernel (90.6 us, absmax 1.22e-4) with ONE change:
// the activation-lo MFMA pass is dropped too -> FULL bf16 compute, 1 pass
// (w * act_bf16). Error budget: act rounding 2^-9 rel adds an independent
// term of the same magnitude as the measured weight-rounding error
// (1.22e-4) -> predicted absmax ~1.7-2.5e-4 vs threshold 3.42e-4
// (threshold = 8 x bf16-eps x max|ref|, designed to admit full-bf16).
// FALLBACK: if absmax > threshold, revert to r14's 2-pass.
// Payoff: MFMA 68->34/point, transition VALU nearly halved (no lo path),
// fragment state halved (fh/fl -> fh) -> lower VGPR -> more waves/SIMD.
// r15 lesson: grid-with-replacement (4096 blocks) beats exact-fit grids;
// bias/X0 stay GLOBAL (LDS pipe is the most-loaded resource at 34
// ds_read_b128/point -- do not add bias reads to it).
//
// Dataflow (m74/m101-verified maps):
//   L0/L1 operand-swapped (A=W, B=act) -> C/D col = lane&31 = neighbor.
//   Transitions in-register: relu -> cvt_pk -> permlane32_swap.
//   L2 normal (A=act, B=W); maxpool = 16 fmax + xor(32); kh halves store the
//   two tuple copies.
//
// Fragment maps (gfx950 32x32x16 bf16):
//   A: row = lane&31, k = 8*(lane>>5)+e ;  B: col = lane&31, same k
//   C/D: col = lane&31, row = (rg&3) + 8*(rg>>2) + 4*(lane>>5)

typedef __attribute__((ext_vector_type(8)))  short bf16x8;
typedef __attribute__((ext_vector_type(16))) float f32x16;

// ws layout, uint16 units (IDENTICAL to rounds 11/14).
// LDS-resident block = first 32768 (64 KiB); lo regions copied but unread:
//  L0 hi (kt 0..3) @ 0      [4 kt][2 tile][64 lane][8 e] = 4096
//  L0 lo           @ 4096
//  L1 hi           @ 8192   [4][2][64][8] = 4096
//  L1 lo           @ 12288
//  L2 hi           @ 16384  [4][4][64][8] = 8192
//  L2 lo           @ 24576
// Global-only tail:
//  L0 xyz-step hi  @ 32768  [2 tile][64][8] = 1024
//  L0 xyz-step lo  @ 33792
//  bias            @ 34816  f32[256]: bias0[64], bias1[64], bias2[128]
#define WS_L0H 0
#define WS_L0L 4096
#define WS_L1H 8192
#define WS_L1L 12288
#define WS_L2H 16384
#define WS_L2L 24576
#define WS_X0H 32768
#define WS_X0L 33792
#define WS_BIAS 34816
#define LDS_U16 32768            // 64 KiB resident in LDS

__device__ inline uint16_t f32_to_bf16_rne(float x) {
    uint32_t u = __float_as_uint(x);
    uint32_t r = (u + 0x7FFFu + ((u >> 16) & 1u)) >> 16;
    return (uint16_t)r;
}
__device__ inline float bf16_hi_f32(uint16_t h) {
    return __uint_as_float(((uint32_t)h) << 16);
}
__device__ inline void split2(float v, uint16_t* hi, uint16_t* lo) {
    uint16_t h = f32_to_bf16_rne(v);
    *hi = h;
    *lo = f32_to_bf16_rne(v - bf16_hi_f32(h));
}

// ---------------- weight prep (runs once per launch, tiny) ----------------
// IDENTICAL to rounds 11/14 (lo regions written but unread by main).
__global__ void prep_weights(
    const float* __restrict__ W0, const float* __restrict__ b0,
    const float* __restrict__ g0, const float* __restrict__ be0,
    const float* __restrict__ W1, const float* __restrict__ b1,
    const float* __restrict__ g1, const float* __restrict__ be1,
    const float* __restrict__ W2, const float* __restrict__ b2,
    const float* __restrict__ g2, const float* __restrict__ be2,
    uint16_t* __restrict__ ws)
{
    const int tid = blockIdx.x * blockDim.x + threadIdx.x;
    const int nth = gridDim.x * blockDim.x;

    for (int i = tid; i < 4096; i += nth) {
        int e = i & 7, lane = (i >> 3) & 63, nt = (i >> 9) & 1, kt = i >> 10;
        int k = kt * 16 + 8 * (lane >> 5) + e;
        int n = nt * 32 + (lane & 31);
        float v = W0[(3 + k) * 64 + n] * g0[n];
        uint16_t hi, lo; split2(v, &hi, &lo);
        ws[WS_L0H + i] = hi; ws[WS_L0L + i] = lo;
    }
    for (int i = tid; i < 1024; i += nth) {
        int e = i & 7, lane = (i >> 3) & 63, nt = i >> 9;
        int k = 64 + 8 * (lane >> 5) + e;
        int n = nt * 32 + (lane & 31);
        float v = (k < 67) ? W0[(k - 64) * 64 + n] * g0[n] : 0.f;
        uint16_t hi, lo; split2(v, &hi, &lo);
        ws[WS_X0H + i] = hi; ws[WS_X0L + i] = lo;
    }
    for (int i = tid; i < 4096; i += nth) {
        int e = i & 7, lane = (i >> 3) & 63, nt = (i >> 9) & 1, kt = i >> 10;
        int k = kt * 16 + 8 * (lane >> 5) + e;
        int n = nt * 32 + (lane & 31);
        float v = W1[k * 64 + n] * g1[n];
        uint16_t hi, lo; split2(v, &hi, &lo);
        ws[WS_L1H + i] = hi; ws[WS_L1L + i] = lo;
    }
    for (int i = tid; i < 8192; i += nth) {
        int e = i & 7, lane = (i >> 3) & 63, nt = (i >> 9) & 3, kt = i >> 11;
        int k = kt * 16 + 8 * (lane >> 5) + e;
        int n = nt * 32 + (lane & 31);
        float v = W2[k * 128 + n] * g2[n];
        uint16_t hi, lo; split2(v, &hi, &lo);
        ws[WS_L2H + i] = hi; ws[WS_L2L + i] = lo;
    }
    float* bias = (float*)(ws + WS_BIAS);
    for (int i = tid; i < 64; i += nth)  bias[i]       = b0[i] * g0[i] + be0[i];
    for (int i = tid; i < 64; i += nth)  bias[64 + i]  = b1[i] * g1[i] + be1[i];
    for (int i = tid; i < 128; i += nth) bias[128 + i] = b2[i] * g2[i] + be2[i];
}

// ---------------- main kernel helpers ----------------
__device__ inline uint32_t cvt_pk_bf16(float a, float b) {
    uint32_t r;
    asm("v_cvt_pk_bf16_f32 %0, %1, %2" : "=v"(r) : "v"(a), "v"(b));
    return r;
}

union frag_u { uint32_t w[4]; bf16x8 v; };

// convert 8 f32 -> bf16x8 (RNE) via packed converts
__device__ inline bf16x8 cvt8(const float* f) {
    frag_u H;
    #pragma unroll
    for (int p2 = 0; p2 < 4; ++p2)
        H.w[p2] = cvt_pk_bf16(f[2 * p2], f[2 * p2 + 1]);
    return H.v;
}

// relu + bf16 convert + permlane32_swap assembly of next layer's K-fragments.
// acc[2] (C/D, col=neighbor) -> fh[4] (kt-indexed K-fragments).
__device__ inline void transition(const f32x16* acc, bf16x8* fh) {
    #pragma unroll
    for (int mt = 0; mt < 2; ++mt) {
        uint32_t H[8];
        #pragma unroll
        for (int w = 0; w < 8; ++w) {
            float a = fmaxf(acc[mt][2 * w],     0.f);
            float b = fmaxf(acc[mt][2 * w + 1], 0.f);
            H[w] = cvt_pk_bf16(a, b);
        }
        #pragma unroll
        for (int ktL = 0; ktL < 2; ++ktL) {
            uint32_t a0 = H[4 * ktL + 0], b0 = H[4 * ktL + 2];
            uint32_t a1 = H[4 * ktL + 1], b1 = H[4 * ktL + 3];
            asm("v_permlane32_swap_b32 %0, %1" : "+v"(a0), "+v"(b0));
            asm("v_permlane32_swap_b32 %0, %1" : "+v"(a1), "+v"(b1));
            frag_u F; F.w[0] = a0; F.w[1] = a1; F.w[2] = b0; F.w[3] = b1;
            fh[mt * 2 + ktL] = F.v;
        }
    }
}

__global__ __launch_bounds__(512)
void pointnet_mfma(
    const float* __restrict__ xyz_proj,      // [B, H*W, 3]
    const float* __restrict__ points_proj,   // [B, H*W, 64]
    const float* __restrict__ xyz_sampled,   // [B, N, 3]
    const int*   __restrict__ nidx,          // [B, N, 32]
    const float* __restrict__ vmask,         // [B, N, 32, 1]
    const uint16_t* __restrict__ wf,
    float* __restrict__ out)
{
    __shared__ uint16_t slds[LDS_U16];       // 64 KiB (identical to r14)

    // ---- cooperative fill: 64 KiB = 4096 uint4; 512 threads x 8 iters ----
    {
        const uint4* src = (const uint4*)wf;
        uint4* dst = (uint4*)slds;
        #pragma unroll
        for (int j = 0; j < 8; ++j)
            dst[threadIdx.x + j * 512] = src[threadIdx.x + j * 512];
    }
    __syncthreads();   // only barrier; waves independent afterwards

    // XCD-aware bijective swizzle (grid 4096, 8 XCDs, 512 blocks per XCD)
    const int bid = blockIdx.x;
    const int swz = (bid & 7) * 512 + (bid >> 3);

    const int t    = threadIdx.x & 63;
    const int widx = threadIdx.x >> 6;       // 0..7
    const int p    = swz * 8 + widx;          // point id in [0, 2*NN)
    const int rb   = (p >> 14) << 16;          // b * HW

    const int r  = t & 31;   // this lane's neighbor (col) all the way through
    const int kh = t >> 5;   // k-half selector

    const bf16x8* L0h = (const bf16x8*)(slds + WS_L0H);
    const bf16x8* L1h = (const bf16x8*)(slds + WS_L1H);
    const bf16x8* L2h = (const bf16x8*)(slds + WS_L2H);
    const bf16x8* X0h = (const bf16x8*)(wf + WS_X0H);   // xyz step: global
    const float*  bias = (const float*)(wf + WS_BIAS);  // bias: global

    // ---- per-neighbor scalars (each lane: its own neighbor) ----
    const int   idx = nidx[(size_t)p * 32 + r];
    const float m   = vmask[(size_t)p * 32 + r];
    float xd0, xd1, xd2;
    {
        const float* xs = xyz_proj + (size_t)(rb + idx) * 3;
        const float* ns = xyz_sampled + (size_t)p * 3;
        xd0 = xs[0] * m - ns[0];
        xd1 = xs[1] * m - ns[1];
        xd2 = xs[2] * m - ns[2];
    }
    const float* rowp = points_proj + (size_t)(rb + idx) * 64 + 8 * kh;

    // ---- layer 0: K = 64 (channels) + 3 (xyz) -> 64, swapped (W=A) ----
    f32x16 acc0[2];
    #pragma unroll
    for (int mt = 0; mt < 2; ++mt)
        #pragma unroll
        for (int q = 0; q < 4; ++q) {
            float4 bq = *(const float4*)(bias + mt * 32 + 4 * kh + 8 * q);
            acc0[mt][4 * q + 0] = bq.x; acc0[mt][4 * q + 1] = bq.y;
            acc0[mt][4 * q + 2] = bq.z; acc0[mt][4 * q + 3] = bq.w;
        }
    #pragma unroll
    for (int kt = 0; kt < 4; ++kt) {
        bf16x8 w0 = L0h[(kt * 2 + 0) * 64 + t];
        bf16x8 w1 = L0h[(kt * 2 + 1) * 64 + t];
        float f[8];
        *(float4*)&f[0] = ((const float4*)(rowp + kt * 16))[0];
        *(float4*)&f[4] = ((const float4*)(rowp + kt * 16))[1];
        #pragma unroll
        for (int e = 0; e < 8; ++e) f[e] *= m;
        bf16x8 bh = cvt8(f);
        acc0[0] = __builtin_amdgcn_mfma_f32_32x32x16_bf16(w0, bh, acc0[0], 0, 0, 0);
        acc0[1] = __builtin_amdgcn_mfma_f32_32x32x16_bf16(w1, bh, acc0[1], 0, 0, 0);
    }
    {   // xyz k-step (k 64..66 live in kh==0 lanes, e<3); weights from global
        bf16x8 w0 = X0h[0 * 64 + t];
        bf16x8 w1 = X0h[1 * 64 + t];
        const bool lo32 = (kh == 0);
        float f[8] = { lo32 ? xd0 : 0.f, lo32 ? xd1 : 0.f, lo32 ? xd2 : 0.f,
                       0.f, 0.f, 0.f, 0.f, 0.f };
        bf16x8 bh = cvt8(f);
        acc0[0] = __builtin_amdgcn_mfma_f32_32x32x16_bf16(w0, bh, acc0[0], 0, 0, 0);
        acc0[1] = __builtin_amdgcn_mfma_f32_32x32x16_bf16(w1, bh, acc0[1], 0, 0, 0);
    }

    // ---- transition 1: in-register relu+cvt+swap -> L1 B-fragments ----
    bf16x8 fh[4];
    transition(acc0, fh);

    // ---- layer 1: 64 -> 64, swapped (W=A) ----
    f32x16 acc1[2];
    #pragma unroll
    for (int mt = 0; mt < 2; ++mt)
        #pragma unroll
        for (int q = 0; q < 4; ++q) {
            float4 bq = *(const float4*)(bias + 64 + mt * 32 + 4 * kh + 8 * q);
            acc1[mt][4 * q + 0] = bq.x; acc1[mt][4 * q + 1] = bq.y;
            acc1[mt][4 * q + 2] = bq.z; acc1[mt][4 * q + 3] = bq.w;
        }
    #pragma unroll
    for (int kt = 0; kt < 4; ++kt) {
        bf16x8 w0 = L1h[(kt * 2 + 0) * 64 + t];
        bf16x8 w1 = L1h[(kt * 2 + 1) * 64 + t];
        acc1[0] = __builtin_amdgcn_mfma_f32_32x32x16_bf16(w0, fh[kt], acc1[0], 0, 0, 0);
        acc1[1] = __builtin_amdgcn_mfma_f32_32x32x16_bf16(w1, fh[kt], acc1[1], 0, 0, 0);
    }

    // ---- transition 2 -> L2 A-fragments (same per-lane layout) ----
    bf16x8 gh[4];
    transition(acc1, gh);

    // ---- layer 2: 64 -> 128, normal (act=A); fused maxpool + store ----
    #pragma unroll
    for (int half = 0; half < 2; ++half) {
        f32x16 acc2[2];
        const float bb0 = bias[128 + (half * 2 + 0) * 32 + r];
        const float bb1 = bias[128 + (half * 2 + 1) * 32 + r];
        #pragma unroll
        for (int i = 0; i < 16; ++i) { acc2[0][i] = bb0; acc2[1][i] = bb1; }
        #pragma unroll
        for (int kt = 0; kt < 4; ++kt) {
            bf16x8 w0 = L2h[(kt * 4 + half * 2 + 0) * 64 + t];
            bf16x8 w1 = L2h[(kt * 4 + half * 2 + 1) * 64 + t];
            acc2[0] = __builtin_amdgcn_mfma_f32_32x32x16_bf16(gh[kt], w0, acc2[0], 0, 0, 0);
            acc2[1] = __builtin_amdgcn_mfma_f32_32x32x16_bf16(gh[kt], w1, acc2[1], 0, 0, 0);
        }
        #pragma unroll
        for (int j = 0; j < 2; ++j) {
            float v = acc2[j][0];
            #pragma unroll
            for (int g = 1; g < 16; ++g) v = fmaxf(v, acc2[j][g]);
            v = fmaxf(v, __shfl_xor(v, 32));   // merge kh halves
            v = fmaxf(v, 0.f);                 // relu commutes with max
            // kh=0 lanes store tuple copy 0, kh=1 lanes store copy 1
            size_t o = (size_t)p * 128 + (half * 2 + j) * 32 + r
                     + (size_t)kh * OUT_HALF;
            out[o] = v;
        }
    }
}

extern "C" void kernel_launch(void* const* d_in, const int* in_sizes, int n_in,
                              void* d_out, int out_size, void* d_ws, size_t ws_size,
                              hipStream_t stream) {
    const float* xyz_proj    = (const float*)d_in[0];
    const float* points_proj = (const float*)d_in[1];
    const float* xyz_sampled = (const float*)d_in[2];
    const int*   neighbor_idx= (const int*)  d_in[3];
    const float* valid_mask  = (const float*)d_in[4];
    const float* W0 = (const float*)d_in[5];
    const float* b0 = (const float*)d_in[6];
    const float* g0 = (const float*)d_in[7];
    const float* be0= (const float*)d_in[8];
    const float* W1 = (const float*)d_in[9];
    const float* b1 = (const float*)d_in[10];
    const float* g1 = (const float*)d_in[11];
    const float* be1= (const float*)d_in[12];
    const float* W2 = (const float*)d_in[13];
    const float* b2 = (const float*)d_in[14];
    const float* g2 = (const float*)d_in[15];
    const float* be2= (const float*)d_in[16];

    uint16_t* ws = (uint16_t*)d_ws;

    prep_weights<<<64, 256, 0, stream>>>(W0, b0, g0, be0,
                                         W1, b1, g1, be1,
                                         W2, b2, g2, be2, ws);

    // 32768 points: 1 per wave, 8 waves per block -> 4096 blocks
    pointnet_mfma<<<4096, 512, 0, stream>>>(
        xyz_proj, points_proj, xyz_sampled, neighbor_idx, valid_mask,
        ws, (float*)d_out);
}

// Round 17
// 78.581 us; speedup vs baseline: 1.1778x; 1.1541x over previous
//
#include <hip/hip_runtime.h>
#include <stdint.h>

// Problem constants
#define NN 16384                  // sampled points per batch (h*w)
#define HW 65536                  // H*W
#define OUT_HALF (2 * NN * 128)   // one tuple element, flat floats
// MLP: 67 -> 64 -> 64 -> 128 (BN folded), maxpool over K=32 neighbors.
//
// Round-17 = EXACT round-16 kernel (90.7 us, absmax 1.22e-4) with TWO bundled
// occupancy changes (r16 showed all pipes <25%, occ 22% -- pure latency bound;
// caps were VGPR=68>64 -> 16 waves/CU and 64KB LDS -> 2 blocks/CU):
//  (1) LDS image compacted to the 32 KiB actually read (hi-only weights).
//      prep kernel and d_ws layout are BYTE-IDENTICAL to r14/r16 -- only the
//      block fill gathers 3 disjoint chunks (avoids r13's prep-compaction
//      trap). 32KB/block -> 4 blocks/CU.
//  (2) __launch_bounds__(512, 8) -> min 8 waves/EU -> forces VGPR <= 64
//      (shave 4 from 68; NOT r4's 102->48 disaster). 32-wave/CU cap.
//  Together: 2x the concurrent gather chains hiding the ~900-cyc random-row
//  latency; fill traffic halves (268 -> 134 MB).
// 1-pass full-bf16 MFMA (r16-proven, absmax 1.22e-4 vs threshold 3.42e-4).
// bias/X0 stay GLOBAL (don't add reads to the LDS pipe).
//
// Dataflow (m74/m101-verified maps):
//   L0/L1 operand-swapped (A=W, B=act) -> C/D col = lane&31 = neighbor.
//   Transitions in-register: relu -> cvt_pk -> permlane32_swap.
//   L2 normal (A=act, B=W); maxpool = 16 fmax + xor(32); kh halves store the
//   two tuple copies.
//
// Fragment maps (gfx950 32x32x16 bf16):
//   A: row = lane&31, k = 8*(lane>>5)+e ;  B: col = lane&31, same k
//   C/D: col = lane&31, row = (rg&3) + 8*(rg>>2) + 4*(lane>>5)

typedef __attribute__((ext_vector_type(8)))  short bf16x8;
typedef __attribute__((ext_vector_type(16))) float f32x16;

// ws layout, uint16 units (IDENTICAL to rounds 11/14/16):
//  L0 hi (kt 0..3) @ 0      [4 kt][2 tile][64 lane][8 e] = 4096
//  L0 lo           @ 4096   (unread)
//  L1 hi           @ 8192
//  L1 lo           @ 12288  (unread)
//  L2 hi           @ 16384
//  L2 lo           @ 24576  (unread)
//  L0 xyz-step hi  @ 32768  [2 tile][64][8] = 1024   (global-read)
//  L0 xyz-step lo  @ 33792  (unread)
//  bias            @ 34816  f32[256]                  (global-read)
#define WS_L0H 0
#define WS_L0L 4096
#define WS_L1H 8192
#define WS_L1L 12288
#define WS_L2H 16384
#define WS_L2L 24576
#define WS_X0H 32768
#define WS_X0L 33792
#define WS_BIAS 34816

// LDS compacted image (hi-only), uint16 units:
#define LDS_L0H 0                 // 4096
#define LDS_L1H 4096              // 4096
#define LDS_L2H 8192              // 8192
#define LDS_U16 16384             // 32 KiB

__device__ inline uint16_t f32_to_bf16_rne(float x) {
    uint32_t u = __float_as_uint(x);
    uint32_t r = (u + 0x7FFFu + ((u >> 16) & 1u)) >> 16;
    return (uint16_t)r;
}
__device__ inline float bf16_hi_f32(uint16_t h) {
    return __uint_as_float(((uint32_t)h) << 16);
}
__device__ inline void split2(float v, uint16_t* hi, uint16_t* lo) {
    uint16_t h = f32_to_bf16_rne(v);
    *hi = h;
    *lo = f32_to_bf16_rne(v - bf16_hi_f32(h));
}

// ---------------- weight prep (runs once per launch, tiny) ----------------
// BYTE-IDENTICAL to rounds 11/14/16.
__global__ void prep_weights(
    const float* __restrict__ W0, const float* __restrict__ b0,
    const float* __restrict__ g0, const float* __restrict__ be0,
    const float* __restrict__ W1, const float* __restrict__ b1,
    const float* __restrict__ g1, const float* __restrict__ be1,
    const float* __restrict__ W2, const float* __restrict__ b2,
    const float* __restrict__ g2, const float* __restrict__ be2,
    uint16_t* __restrict__ ws)
{
    const int tid = blockIdx.x * blockDim.x + threadIdx.x;
    const int nth = gridDim.x * blockDim.x;

    for (int i = tid; i < 4096; i += nth) {
        int e = i & 7, lane = (i >> 3) & 63, nt = (i >> 9) & 1, kt = i >> 10;
        int k = kt * 16 + 8 * (lane >> 5) + e;
        int n = nt * 32 + (lane & 31);
        float v = W0[(3 + k) * 64 + n] * g0[n];
        uint16_t hi, lo; split2(v, &hi, &lo);
        ws[WS_L0H + i] = hi; ws[WS_L0L + i] = lo;
    }
    for (int i = tid; i < 1024; i += nth) {
        int e = i & 7, lane = (i >> 3) & 63, nt = i >> 9;
        int k = 64 + 8 * (lane >> 5) + e;
        int n = nt * 32 + (lane & 31);
        float v = (k < 67) ? W0[(k - 64) * 64 + n] * g0[n] : 0.f;
        uint16_t hi, lo; split2(v, &hi, &lo);
        ws[WS_X0H + i] = hi; ws[WS_X0L + i] = lo;
    }
    for (int i = tid; i < 4096; i += nth) {
        int e = i & 7, lane = (i >> 3) & 63, nt = (i >> 9) & 1, kt = i >> 10;
        int k = kt * 16 + 8 * (lane >> 5) + e;
        int n = nt * 32 + (lane & 31);
        float v = W1[k * 64 + n] * g1[n];
        uint16_t hi, lo; split2(v, &hi, &lo);
        ws[WS_L1H + i] = hi; ws[WS_L1L + i] = lo;
    }
    for (int i = tid; i < 8192; i += nth) {
        int e = i & 7, lane = (i >> 3) & 63, nt = (i >> 9) & 3, kt = i >> 11;
        int k = kt * 16 + 8 * (lane >> 5) + e;
        int n = nt * 32 + (lane & 31);
        float v = W2[k * 128 + n] * g2[n];
        uint16_t hi, lo; split2(v, &hi, &lo);
        ws[WS_L2H + i] = hi; ws[WS_L2L + i] = lo;
    }
    float* bias = (float*)(ws + WS_BIAS);
    for (int i = tid; i < 64; i += nth)  bias[i]       = b0[i] * g0[i] + be0[i];
    for (int i = tid; i < 64; i += nth)  bias[64 + i]  = b1[i] * g1[i] + be1[i];
    for (int i = tid; i < 128; i += nth) bias[128 + i] = b2[i] * g2[i] + be2[i];
}

// ---------------- main kernel helpers ----------------
__device__ inline uint32_t cvt_pk_bf16(float a, float b) {
    uint32_t r;
    asm("v_cvt_pk_bf16_f32 %0, %1, %2" : "=v"(r) : "v"(a), "v"(b));
    return r;
}

union frag_u { uint32_t w[4]; bf16x8 v; };

// convert 8 f32 -> bf16x8 (RNE) via packed converts
__device__ inline bf16x8 cvt8(const float* f) {
    frag_u H;
    #pragma unroll
    for (int p2 = 0; p2 < 4; ++p2)
        H.w[p2] = cvt_pk_bf16(f[2 * p2], f[2 * p2 + 1]);
    return H.v;
}

// relu + bf16 convert + permlane32_swap assembly of next layer's K-fragments.
__device__ inline void transition(const f32x16* acc, bf16x8* fh) {
    #pragma unroll
    for (int mt = 0; mt < 2; ++mt) {
        uint32_t H[8];
        #pragma unroll
        for (int w = 0; w < 8; ++w) {
            float a = fmaxf(acc[mt][2 * w],     0.f);
            float b = fmaxf(acc[mt][2 * w + 1], 0.f);
            H[w] = cvt_pk_bf16(a, b);
        }
        #pragma unroll
        for (int ktL = 0; ktL < 2; ++ktL) {
            uint32_t a0 = H[4 * ktL + 0], b0 = H[4 * ktL + 2];
            uint32_t a1 = H[4 * ktL + 1], b1 = H[4 * ktL + 3];
            asm("v_permlane32_swap_b32 %0, %1" : "+v"(a0), "+v"(b0));
            asm("v_permlane32_swap_b32 %0, %1" : "+v"(a1), "+v"(b1));
            frag_u F; F.w[0] = a0; F.w[1] = a1; F.w[2] = b0; F.w[3] = b1;
            fh[mt * 2 + ktL] = F.v;
        }
    }
}

__global__ __launch_bounds__(512, 8)
void pointnet_mfma(
    const float* __restrict__ xyz_proj,      // [B, H*W, 3]
    const float* __restrict__ points_proj,   // [B, H*W, 64]
    const float* __restrict__ xyz_sampled,   // [B, N, 3]
    const int*   __restrict__ nidx,          // [B, N, 32]
    const float* __restrict__ vmask,         // [B, N, 32, 1]
    const uint16_t* __restrict__ wf,
    float* __restrict__ out)
{
    __shared__ __align__(16) uint16_t slds[LDS_U16];   // 32 KiB hi-only image

    // ---- cooperative fill: 3 disjoint hi chunks -> contiguous LDS ----
    // uint4 units (8 u16): L0h src[0,512)->dst[0,512); L1h src[1024,1536)->
    // dst[512,1024); L2h src[2048,3072)->dst[1024,2048).
    {
        const uint4* src = (const uint4*)wf;
        uint4* dst = (uint4*)slds;
        #pragma unroll
        for (int j = 0; j < 4; ++j) {
            int i = threadIdx.x + j * 512;
            int s = (i < 512) ? i : (i < 1024 ? i + 512 : i + 1024);
            dst[i] = src[s];
        }
    }
    __syncthreads();   // only barrier; waves independent afterwards

    // XCD-aware bijective swizzle (grid 4096, 8 XCDs, 512 blocks per XCD)
    const int bid = blockIdx.x;
    const int swz = (bid & 7) * 512 + (bid >> 3);

    const int t    = threadIdx.x & 63;
    const int widx = threadIdx.x >> 6;       // 0..7
    const int p    = swz * 8 + widx;          // point id in [0, 2*NN)
    const int rb   = (p >> 14) << 16;          // b * HW

    const int r  = t & 31;   // this lane's neighbor (col) all the way through
    const int kh = t >> 5;   // k-half selector

    const bf16x8* L0h = (const bf16x8*)(slds + LDS_L0H);
    const bf16x8* L1h = (const bf16x8*)(slds + LDS_L1H);
    const bf16x8* L2h = (const bf16x8*)(slds + LDS_L2H);
    const bf16x8* X0h = (const bf16x8*)(wf + WS_X0H);   // xyz step: global
    const float*  bias = (const float*)(wf + WS_BIAS);  // bias: global

    // ---- per-neighbor scalars (each lane: its own neighbor) ----
    const int   idx = nidx[(size_t)p * 32 + r];
    const float m   = vmask[(size_t)p * 32 + r];
    float xd0, xd1, xd2;
    {
        const float* xs = xyz_proj + (size_t)(rb + idx) * 3;
        const float* ns = xyz_sampled + (size_t)p * 3;
        xd0 = xs[0] * m - ns[0];
        xd1 = xs[1] * m - ns[1];
        xd2 = xs[2] * m - ns[2];
    }
    const float* rowp = points_proj + (size_t)(rb + idx) * 64 + 8 * kh;

    // ---- layer 0: K = 64 (channels) + 3 (xyz) -> 64, swapped (W=A) ----
    f32x16 acc0[2];
    #pragma unroll
    for (int mt = 0; mt < 2; ++mt)
        #pragma unroll
        for (int q = 0; q < 4; ++q) {
            float4 bq = *(const float4*)(bias + mt * 32 + 4 * kh + 8 * q);
            acc0[mt][4 * q + 0] = bq.x; acc0[mt][4 * q + 1] = bq.y;
            acc0[mt][4 * q + 2] = bq.z; acc0[mt][4 * q + 3] = bq.w;
        }
    #pragma unroll
    for (int kt = 0; kt < 4; ++kt) {
        bf16x8 w0 = L0h[(kt * 2 + 0) * 64 + t];
        bf16x8 w1 = L0h[(kt * 2 + 1) * 64 + t];
        float f[8];
        *(float4*)&f[0] = ((const float4*)(rowp + kt * 16))[0];
        *(float4*)&f[4] = ((const float4*)(rowp + kt * 16))[1];
        #pragma unroll
        for (int e = 0; e < 8; ++e) f[e] *= m;
        bf16x8 bh = cvt8(f);
        acc0[0] = __builtin_amdgcn_mfma_f32_32x32x16_bf16(w0, bh, acc0[0], 0, 0, 0);
        acc0[1] = __builtin_amdgcn_mfma_f32_32x32x16_bf16(w1, bh, acc0[1], 0, 0, 0);
    }
    {   // xyz k-step (k 64..66 live in kh==0 lanes, e<3); weights from global
        bf16x8 w0 = X0h[0 * 64 + t];
        bf16x8 w1 = X0h[1 * 64 + t];
        const bool lo32 = (kh == 0);
        float f[8] = { lo32 ? xd0 : 0.f, lo32 ? xd1 : 0.f, lo32 ? xd2 : 0.f,
                       0.f, 0.f, 0.f, 0.f, 0.f };
        bf16x8 bh = cvt8(f);
        acc0[0] = __builtin_amdgcn_mfma_f32_32x32x16_bf16(w0, bh, acc0[0], 0, 0, 0);
        acc0[1] = __builtin_amdgcn_mfma_f32_32x32x16_bf16(w1, bh, acc0[1], 0, 0, 0);
    }

    // ---- transition 1: in-register relu+cvt+swap -> L1 B-fragments ----
    bf16x8 fh[4];
    transition(acc0, fh);

    // ---- layer 1: 64 -> 64, swapped (W=A) ----
    f32x16 acc1[2];
    #pragma unroll
    for (int mt = 0; mt < 2; ++mt)
        #pragma unroll
        for (int q = 0; q < 4; ++q) {
            float4 bq = *(const float4*)(bias + 64 + mt * 32 + 4 * kh + 8 * q);
            acc1[mt][4 * q + 0] = bq.x; acc1[mt][4 * q + 1] = bq.y;
            acc1[mt][4 * q + 2] = bq.z; acc1[mt][4 * q + 3] = bq.w;
        }
    #pragma unroll
    for (int kt = 0; kt < 4; ++kt) {
        bf16x8 w0 = L1h[(kt * 2 + 0) * 64 + t];
        bf16x8 w1 = L1h[(kt * 2 + 1) * 64 + t];
        acc1[0] = __builtin_amdgcn_mfma_f32_32x32x16_bf16(w0, fh[kt], acc1[0], 0, 0, 0);
        acc1[1] = __builtin_amdgcn_mfma_f32_32x32x16_bf16(w1, fh[kt], acc1[1], 0, 0, 0);
    }

    // ---- transition 2 -> L2 A-fragments (same per-lane layout) ----
    bf16x8 gh[4];
    transition(acc1, gh);

    // ---- layer 2: 64 -> 128, normal (act=A); fused maxpool + store ----
    #pragma unroll
    for (int half = 0; half < 2; ++half) {
        f32x16 acc2[2];
        const float bb0 = bias[128 + (half * 2 + 0) * 32 + r];
        const float bb1 = bias[128 + (half * 2 + 1) * 32 + r];
        #pragma unroll
        for (int i = 0; i < 16; ++i) { acc2[0][i] = bb0; acc2[1][i] = bb1; }
        #pragma unroll
        for (int kt = 0; kt < 4; ++kt) {
            bf16x8 w0 = L2h[(kt * 4 + half * 2 + 0) * 64 + t];
            bf16x8 w1 = L2h[(kt * 4 + half * 2 + 1) * 64 + t];
            acc2[0] = __builtin_amdgcn_mfma_f32_32x32x16_bf16(gh[kt], w0, acc2[0], 0, 0, 0);
            acc2[1] = __builtin_amdgcn_mfma_f32_32x32x16_bf16(gh[kt], w1, acc2[1], 0, 0, 0);
        }
        #pragma unroll
        for (int j = 0; j < 2; ++j) {
            float v = acc2[j][0];
            #pragma unroll
            for (int g = 1; g < 16; ++g) v = fmaxf(v, acc2[j][g]);
            v = fmaxf(v, __shfl_xor(v, 32));   // merge kh halves
            v = fmaxf(v, 0.f);                 // relu commutes with max
            // kh=0 lanes store tuple copy 0, kh=1 lanes store copy 1
            size_t o = (size_t)p * 128 + (half * 2 + j) * 32 + r
                     + (size_t)kh * OUT_HALF;
            out[o] = v;
        }
    }
}

extern "C" void kernel_launch(void* const* d_in, const int* in_sizes, int n_in,
                              void* d_out, int out_size, void* d_ws, size_t ws_size,
                              hipStream_t stream) {
    const float* xyz_proj    = (const float*)d_in[0];
    const float* points_proj = (const float*)d_in[1];
    const float* xyz_sampled = (const float*)d_in[2];
    const int*   neighbor_idx= (const int*)  d_in[3];
    const float* valid_mask  = (const float*)d_in[4];
    const float* W0 = (const float*)d_in[5];
    const float* b0 = (const float*)d_in[6];
    const float* g0 = (const float*)d_in[7];
    const float* be0= (const float*)d_in[8];
    const float* W1 = (const float*)d_in[9];
    const float* b1 = (const float*)d_in[10];
    const float* g1 = (const float*)d_in[11];
    const float* be1= (const float*)d_in[12];
    const float* W2 = (const float*)d_in[13];
    const float* b2 = (const float*)d_in[14];
    const float* g2 = (const float*)d_in[15];
    const float* be2= (const float*)d_in[16];

    uint16_t* ws = (uint16_t*)d_ws;

    prep_weights<<<64, 256, 0, stream>>>(W0, b0, g0, be0,
                                         W1, b1, g1, be1,
                                         W2, b2, g2, be2, ws);

    // 32768 points: 1 per wave, 8 waves per block -> 4096 blocks
    pointnet_mfma<<<4096, 512, 0, stream>>>(
        xyz_proj, points_proj, xyz_sampled, neighbor_idx, valid_mask,
        ws, (float*)d_out);
}